// Round 7
// baseline (349.571 us; speedup 1.0000x reference)
//
#include <hip/hip_runtime.h>
#include <hip/hip_bf16.h>
#include <stdint.h>

#define TB 8
#define TC 256
#define TH 120
#define TW 120
#define THW 14400
#define TOC 256
#define PH 122
#define PW 122

typedef short bf16x8 __attribute__((ext_vector_type(8)));
typedef float f32x4 __attribute__((ext_vector_type(4)));

// ---- workspace layout (bytes) ----
#define OUTP_BYTES ((size_t)TB * PH * PW * TC * 2)
#define YP_OFF     OUTP_BYTES
#define DK_OFF     (YP_OFF + (size_t)TB * TC * 9 * 4)
#define WP_OFF     (DK_OFF + (size_t)TB * TC * 9 * 4)

// merged: blocks 0..483 zero the outP halo ring; 484..2787 transpose fuse_w.
__global__ void prep_kernel(const float* __restrict__ fuse_w,
                            __hip_bfloat16* __restrict__ Wp,
                            char* __restrict__ outP) {
    int blk = blockIdx.x;
    if (blk < 484) {
        int i = blk * 256 + threadIdx.x;
        int pos_idx = i >> 5, part = i & 31;
        int b = pos_idx / 484; int k = pos_idx - b * 484;
        int h, w;
        if (k < 122)      { h = 0;   w = k; }
        else if (k < 244) { h = 121; w = k - 122; }
        else { int m = k - 244; h = 1 + (m >> 1); w = (m & 1) ? 121 : 0; }
        size_t pos = ((size_t)b * PH + h) * PW + w;
        uint4 z; z.x = 0u; z.y = 0u; z.z = 0u; z.w = 0u;
        *(uint4*)(outP + pos * 512 + part * 16) = z;
    } else {
        int i = (blk - 484) * 256 + threadIdx.x;   // exactly 589824
        int ij = i >> 16;
        int oc = (i >> 8) & 255;
        int c  = i & 255;
        Wp[i] = __float2bfloat16(fuse_w[(oc * 256 + c) * 9 + ij]);
    }
}

__global__ __launch_bounds__(128) void pool_kernel(const float* __restrict__ y,
                                                   float* __restrict__ yp) {
    int bc = blockIdx.x, t = threadIdx.x;
    __shared__ float pr[120][4];
    __shared__ float p2[9][8];
    const float* src = y + (size_t)bc * THW;
    if (t < 120) {
        const float4* row = (const float4*)(src + t * TW);
        float s0 = 0.f, s1 = 0.f, s2 = 0.f;
        #pragma unroll
        for (int j = 0; j < 10; ++j)  { float4 v = row[j]; s0 += (v.x + v.y) + (v.z + v.w); }
        #pragma unroll
        for (int j = 10; j < 20; ++j) { float4 v = row[j]; s1 += (v.x + v.y) + (v.z + v.w); }
        #pragma unroll
        for (int j = 20; j < 30; ++j) { float4 v = row[j]; s2 += (v.x + v.y) + (v.z + v.w); }
        pr[t][0] = s0; pr[t][1] = s1; pr[t][2] = s2;
    }
    __syncthreads();
    if (t < 72) {
        int bin = t >> 3, ch = t & 7;
        int bh = bin / 3, bw = bin - bh * 3;
        float a = 0.f;
        #pragma unroll
        for (int r = 0; r < 5; ++r) a += pr[bh * 40 + ch * 5 + r][bw];
        p2[bin][ch] = a;
    }
    __syncthreads();
    if (t < 9) {
        float a = 0.f;
        #pragma unroll
        for (int j = 0; j < 8; ++j) a += p2[t][j];
        yp[bc * 9 + t] = a * (1.f / 1600.f);
    }
}

// gen split: 64 blocks = (b, ocg of 32 oc); thread = (cseg 0..7, ocl 0..31)
__global__ __launch_bounds__(256) void gen_kernel(const float* __restrict__ yp,
        const float* __restrict__ gen_w, const float* __restrict__ gen_b,
        float* __restrict__ dk) {
    int blk = blockIdx.x;
    int b = blk >> 3, ocg = blk & 7;
    int t = threadIdx.x;
    int ocl = t & 31, cseg = t >> 5;
    int oc = ocg * 32 + ocl;
    __shared__ float yps[TC * 9];
    for (int i = t; i < TC * 9; i += 256) yps[i] = yp[b * TC * 9 + i];
    __syncthreads();
    float acc[9];
    #pragma unroll
    for (int j = 0; j < 9; ++j) acc[j] = 0.f;
    const float* wrow = gen_w + (size_t)oc * TC + cseg * 32;
    for (int c = 0; c < 32; ++c) {
        float w = wrow[c];
        const float* yrow = &yps[(cseg * 32 + c) * 9];
        #pragma unroll
        for (int j = 0; j < 9; ++j) acc[j] += w * yrow[j];
    }
    __shared__ float red[8][32][9];
    #pragma unroll
    for (int j = 0; j < 9; ++j) red[cseg][ocl][j] = acc[j];
    __syncthreads();
    for (int st = 4; st > 0; st >>= 1) {
        if (cseg < st) {
            #pragma unroll
            for (int j = 0; j < 9; ++j) red[cseg][ocl][j] += red[cseg + st][ocl][j];
        }
        __syncthreads();
    }
    if (cseg == 0) {
        float bias = gen_b[oc];
        #pragma unroll
        for (int j = 0; j < 9; ++j)
            dk[((size_t)b * TC + oc) * 9 + j] = red[0][ocl][j] + bias;
    }
}

// depthwise dynamic 3x3 -> channel-last padded bf16, pair-pipelined flush.
__global__ __launch_bounds__(1024) void dw_kernel(const float* __restrict__ x,
        const float* __restrict__ dk, __hip_bfloat16* __restrict__ outP) {
    int bid = blockIdx.x;
    int hs = bid & 7;
    int cc = (bid >> 3) & 7;
    int b  = bid >> 6;
    int t = threadIdx.x;
    int c  = t >> 5;
    int wq = t & 31;
    bool active = wq < 30;
    int w0 = wq * 4;
    int cg = cc * 32 + c;
    const float* xp = x + (size_t)(b * TC + cg) * THW;
    const float* dkp = dk + (size_t)(b * TC + cg) * 9;
    float k0[3], k1[3], k2[3];
    #pragma unroll
    for (int j = 0; j < 3; ++j) { k0[j] = dkp[j]; k1[j] = dkp[3 + j]; k2[j] = dkp[6 + j]; }

    __shared__ __align__(16) __hip_bfloat16 stage[2][2][32][124];

    int h0 = hs * 15;
    float A[6], B[6], C[6];
    auto loadrow = [&](int hh, float* V) {
        if (hh < 0 || hh >= TH) {
            #pragma unroll
            for (int j = 0; j < 6; ++j) V[j] = 0.f;
            return;
        }
        const float* row = xp + hh * TW;
        float4 v = *(const float4*)(row + w0);
        V[1] = v.x; V[2] = v.y; V[3] = v.z; V[4] = v.w;
        V[0] = (wq > 0)  ? row[w0 - 1] : 0.f;
        V[5] = (wq < 29) ? row[w0 + 4] : 0.f;
    };
    auto comp = [&](int r, int par, int sub) {
        if (!active) return;
        loadrow(h0 + r + 1, C);
        ushort4 pk;
        #pragma unroll
        for (int i = 0; i < 4; ++i) {
            float o = A[i] * k0[0] + A[i + 1] * k0[1] + A[i + 2] * k0[2]
                    + B[i] * k1[0] + B[i + 1] * k1[1] + B[i + 2] * k1[2]
                    + C[i] * k2[0] + C[i + 1] * k2[1] + C[i + 2] * k2[2];
            __hip_bfloat16 hb = __float2bfloat16(o);
            ushort u = *(ushort*)&hb;
            if (i == 0) pk.x = u; else if (i == 1) pk.y = u;
            else if (i == 2) pk.z = u; else pk.w = u;
        }
        *(ushort4*)&stage[par][sub][c][w0] = pk;
        #pragma unroll
        for (int j = 0; j < 6; ++j) { A[j] = B[j]; B[j] = C[j]; }
    };
    auto flushrow = [&](int r, int par, int sub, int tt) {
        int w = tt >> 2, part = tt & 3;
        ushort vals[8];
        #pragma unroll
        for (int j = 0; j < 8; ++j) vals[j] = *(const ushort*)&stage[par][sub][part * 8 + j][w];
        uint4 o;
        o.x = (uint)vals[0] | ((uint)vals[1] << 16);
        o.y = (uint)vals[2] | ((uint)vals[3] << 16);
        o.z = (uint)vals[4] | ((uint)vals[5] << 16);
        o.w = (uint)vals[6] | ((uint)vals[7] << 16);
        size_t pos = ((size_t)b * PH + (h0 + r + 1)) * PW + (w + 1);
        *(uint4*)((char*)outP + pos * 512 + cc * 64 + part * 16) = o;
    };

    if (active) { loadrow(h0 - 1, A); loadrow(h0, B); }
    comp(0, 0, 0); comp(1, 0, 1);
    __syncthreads();
    #pragma unroll 1
    for (int p = 1; p < 8; ++p) {
        int r0 = 2 * p;
        comp(r0, p & 1, 0);
        if (r0 + 1 < 15) comp(r0 + 1, p & 1, 1);
        if (t < 960) {
            int fr = t >= 480 ? 1 : 0;
            int tt = t - fr * 480;
            flushrow(2 * (p - 1) + fr, (p - 1) & 1, fr, tt);
        }
        __syncthreads();
    }
    if (t < 480) flushrow(14, 1, 0, t);
}

typedef const __attribute__((address_space(1))) char* gas_t;
typedef __attribute__((address_space(3))) char* las_t;
__device__ __forceinline__ void gload16(const char* g, char* l) {
    __builtin_amdgcn_global_load_lds((gas_t)g, (las_t)l, 16, 0, 0);
}
__device__ __forceinline__ void barrier_() {
    asm volatile("" ::: "memory");
    __builtin_amdgcn_s_barrier();
    asm volatile("" ::: "memory");
}

// Implicit GEMM v3: 128x128 tile, BK=64, **2 waves (128 thr), per-wave 128m x 64oc**
// (43 FLOP per LDS byte vs 32 for 64x64/wave).  Single-buffer 32KB LDS (m97-style
// full-drain loop) -> 4 blocks/CU; same staging map / XOR swizzle / XCD swizzle
// as the proven R3 kernel.
__global__ __launch_bounds__(128) void gemm_kernel(
        const __hip_bfloat16* __restrict__ outP,
        const __hip_bfloat16* __restrict__ Wp,
        const float* __restrict__ fuse_b,
        float* __restrict__ res) {
    __shared__ __align__(16) char lds[32768];   // A 16K | B 16K
    const int t = threadIdx.x;        // 0..127
    const int lane = t & 63;
    const int wn = t >> 6;            // wave = oc half (0..1)

    const int bid0 = blockIdx.x;
    const int logical = (bid0 & 7) * 225 + (bid0 >> 3);   // 1800 % 8 == 0
    const int bn = logical & 1;       // oc tile (0..1)
    const int bm = logical >> 1;      // m tile (0..899)

    const char* gI = (const char*)outP;
    const char* gW = (const char*)Wp;

    // ---- staging: seg q, thread t covers LDS bytes q*2048 + t*16 of a 16KB half
    // row p = q*16 + (t>>3); byte-in-row rb=(t&7)*16; source rb' = rb ^ ((p&7)<<4)
    const int srb = (((t & 7) ^ ((t >> 3) & 7)) << 4);
    int srcA[8], srcB[8];
    #pragma unroll
    for (int q = 0; q < 8; ++q) {
        int p = q * 16 + (t >> 3);
        int m = bm * 128 + p;
        int b = m / THW; int r = m - b * THW;
        int h = r / TW;  int w = r - h * TW;
        srcA[q] = (((b * PH + h) * PW + w) << 9) + srb;
        srcB[q] = ((bn * 128 + p) << 9) + srb;
    }

    // ---- read-side: addr = row*128 + (kbyte ^ ((row&7)<<4)); row&7 == lane&7
    const int sw  = (lane & 7) << 4;
    const int klo = (lane >> 4) << 4;
    int aA[8], aB[4];
    #pragma unroll
    for (int f = 0; f < 8; ++f) aA[f] = (f * 16 + (lane & 15)) * 128;
    #pragma unroll
    for (int g = 0; g < 4; ++g) aB[g] = 16384 + (wn * 64 + g * 16 + (lane & 15)) * 128;

    f32x4 acc[8][4];
    #pragma unroll
    for (int f = 0; f < 8; ++f) {
        #pragma unroll
        for (int g = 0; g < 4; ++g) { f32x4 z = {0.f,0.f,0.f,0.f}; acc[f][g] = z; }
    }

    auto STAGE = [&](int s) {
        int ij = s >> 2;
        int c0b = (s & 3) << 7;
        int di = ij / 3, dj = ij - di * 3;
        int offI = ((di * PW + dj) << 9) + c0b;
        int offW = (ij << 17) + c0b;
        #pragma unroll
        for (int q = 0; q < 8; ++q)
            gload16(gI + srcA[q] + offI, lds + q * 2048 + t * 16);
        #pragma unroll
        for (int q = 0; q < 8; ++q)
            gload16(gW + srcB[q] + offW, lds + 16384 + q * 2048 + t * 16);
    };
    auto COMPUTE = [&]() {
        #pragma unroll
        for (int kk = 0; kk < 2; ++kk) {
            int cx = (kk * 64 + klo) ^ sw;
            bf16x8 fA[8], fB[4];
            #pragma unroll
            for (int f = 0; f < 8; ++f) fA[f] = *(const bf16x8*)(lds + aA[f] + cx);
            #pragma unroll
            for (int g = 0; g < 4; ++g) fB[g] = *(const bf16x8*)(lds + aB[g] + cx);
            __builtin_amdgcn_s_setprio(1);
            #pragma unroll
            for (int f = 0; f < 8; ++f) {
                #pragma unroll
                for (int g = 0; g < 4; ++g)
                    acc[f][g] = __builtin_amdgcn_mfma_f32_16x16x32_bf16(
                        fB[g], fA[f], acc[f][g], 0, 0, 0);
            }
            __builtin_amdgcn_s_setprio(0);
        }
    };

    STAGE(0);
    #pragma unroll 1
    for (int s = 0; s < 35; ++s) {
        asm volatile("s_waitcnt vmcnt(0)" ::: "memory");
        barrier_();
        COMPUTE();
        barrier_();
        STAGE(s + 1);
    }
    asm volatile("s_waitcnt vmcnt(0)" ::: "memory");
    barrier_();
    COMPUTE();

    // ---- epilogue: col(lane&15)=m, row-group((lane>>4)*4+j)=oc (m89 layout)
    int baseM[8];
    #pragma unroll
    for (int f = 0; f < 8; ++f) {
        int m = bm * 128 + f * 16 + (lane & 15);
        int b = m / THW; int r = m - b * THW;
        baseM[f] = b * (TOC * THW) + r;
    }
    const int oc0 = bn * 128 + wn * 64 + ((lane >> 4) << 2);
    float bias[4][4];
    #pragma unroll
    for (int g = 0; g < 4; ++g) {
        #pragma unroll
        for (int j = 0; j < 4; ++j) bias[g][j] = fuse_b[oc0 + g * 16 + j];
    }
    #pragma unroll
    for (int g = 0; g < 4; ++g) {
        #pragma unroll
        for (int f = 0; f < 8; ++f) {
            #pragma unroll
            for (int j = 0; j < 4; ++j)
                res[baseM[f] + (oc0 + g * 16 + j) * THW] = acc[f][g][j] + bias[g][j];
        }
    }
}

extern "C" void kernel_launch(void* const* d_in, const int* in_sizes, int n_in,
                              void* d_out, int out_size, void* d_ws, size_t ws_size,
                              hipStream_t stream) {
    const float* x      = (const float*)d_in[0];
    const float* y      = (const float*)d_in[1];
    const float* gen_w  = (const float*)d_in[2];
    const float* gen_b  = (const float*)d_in[3];
    const float* fuse_w = (const float*)d_in[4];
    const float* fuse_b = (const float*)d_in[5];
    float* out = (float*)d_out;
    char* ws = (char*)d_ws;

    __hip_bfloat16* outP = (__hip_bfloat16*)(ws);
    float* yp = (float*)(ws + YP_OFF);
    float* dk = (float*)(ws + DK_OFF);
    __hip_bfloat16* Wp = (__hip_bfloat16*)(ws + WP_OFF);

    prep_kernel<<<2788, 256, 0, stream>>>(fuse_w, Wp, (char*)outP);
    pool_kernel<<<TB * TC, 128, 0, stream>>>(y, yp);
    gen_kernel<<<64, 256, 0, stream>>>(yp, gen_w, gen_b, dk);
    dw_kernel<<<512, 1024, 0, stream>>>(x, dk, outP);
    gemm_kernel<<<1800, 128, 0, stream>>>(outP, Wp, fuse_b, out);
}

// Round 8
// 216.937 us; speedup vs baseline: 1.6114x; 1.6114x over previous
//
#include <hip/hip_runtime.h>
#include <hip/hip_bf16.h>
#include <stdint.h>

#define TB 8
#define TC 256
#define TH 120
#define TW 120
#define THW 14400
#define TOC 256
#define PH 122
#define PW 122

typedef short bf16x8 __attribute__((ext_vector_type(8)));
typedef float f32x4 __attribute__((ext_vector_type(4)));

// ---- workspace layout (bytes) ----
#define OUTP_BYTES ((size_t)TB * PH * PW * TC * 2)
#define YP_OFF     OUTP_BYTES
#define DK_OFF     (YP_OFF + (size_t)TB * TC * 9 * 4)
#define WP_OFF     (DK_OFF + (size_t)TB * TC * 9 * 4)

// Fat kernel: blocks 0..2047 = pool; 2048..3015 = halo zero; 3016..7623 = wprep.
__global__ __launch_bounds__(128) void pool_prep_kernel(
        const float* __restrict__ y, float* __restrict__ yp,
        const float* __restrict__ fuse_w, __hip_bfloat16* __restrict__ Wp,
        char* __restrict__ outP) {
    int blk = blockIdx.x;
    int t = threadIdx.x;
    if (blk < 2048) {
        // ---- pool: yp[b][c][ij] = mean of 40x40 block
        int bc = blk;
        __shared__ float pr[120][4];
        __shared__ float p2[9][8];
        const float* src = y + (size_t)bc * THW;
        if (t < 120) {
            const float4* row = (const float4*)(src + t * TW);
            float s0 = 0.f, s1 = 0.f, s2 = 0.f;
            #pragma unroll
            for (int j = 0; j < 10; ++j)  { float4 v = row[j]; s0 += (v.x + v.y) + (v.z + v.w); }
            #pragma unroll
            for (int j = 10; j < 20; ++j) { float4 v = row[j]; s1 += (v.x + v.y) + (v.z + v.w); }
            #pragma unroll
            for (int j = 20; j < 30; ++j) { float4 v = row[j]; s2 += (v.x + v.y) + (v.z + v.w); }
            pr[t][0] = s0; pr[t][1] = s1; pr[t][2] = s2;
        }
        __syncthreads();
        if (t < 72) {
            int bin = t >> 3, ch = t & 7;
            int bh = bin / 3, bw = bin - bh * 3;
            float a = 0.f;
            #pragma unroll
            for (int r = 0; r < 5; ++r) a += pr[bh * 40 + ch * 5 + r][bw];
            p2[bin][ch] = a;
        }
        __syncthreads();
        if (t < 9) {
            float a = 0.f;
            #pragma unroll
            for (int j = 0; j < 8; ++j) a += p2[t][j];
            yp[bc * 9 + t] = a * (1.f / 1600.f);
        }
    } else if (blk < 3016) {
        // ---- halo zero: 123904 uint4 slots
        int i = (blk - 2048) * 128 + t;
        int pos_idx = i >> 5, part = i & 31;
        int b = pos_idx / 484; int k = pos_idx - b * 484;
        int h, w;
        if (k < 122)      { h = 0;   w = k; }
        else if (k < 244) { h = 121; w = k - 122; }
        else { int m = k - 244; h = 1 + (m >> 1); w = (m & 1) ? 121 : 0; }
        size_t pos = ((size_t)b * PH + h) * PW + w;
        uint4 z; z.x = 0u; z.y = 0u; z.z = 0u; z.w = 0u;
        *(uint4*)(outP + pos * 512 + part * 16) = z;
    } else {
        // ---- wprep: Wp[ij][oc][c] = bf16(fuse_w[oc][c][ij]), 589824 elems
        int i = (blk - 3016) * 128 + t;
        int ij = i >> 16;
        int oc = (i >> 8) & 255;
        int c  = i & 255;
        Wp[i] = __float2bfloat16(fuse_w[(oc * 256 + c) * 9 + ij]);
    }
}

// gen split: 64 blocks = (b, ocg of 32 oc); thread = (cseg 0..7, ocl 0..31)
__global__ __launch_bounds__(256) void gen_kernel(const float* __restrict__ yp,
        const float* __restrict__ gen_w, const float* __restrict__ gen_b,
        float* __restrict__ dk) {
    int blk = blockIdx.x;
    int b = blk >> 3, ocg = blk & 7;
    int t = threadIdx.x;
    int ocl = t & 31, cseg = t >> 5;
    int oc = ocg * 32 + ocl;
    __shared__ float yps[TC * 9];
    for (int i = t; i < TC * 9; i += 256) yps[i] = yp[b * TC * 9 + i];
    __syncthreads();
    float acc[9];
    #pragma unroll
    for (int j = 0; j < 9; ++j) acc[j] = 0.f;
    const float* wrow = gen_w + (size_t)oc * TC + cseg * 32;
    for (int c = 0; c < 32; ++c) {
        float w = wrow[c];
        const float* yrow = &yps[(cseg * 32 + c) * 9];
        #pragma unroll
        for (int j = 0; j < 9; ++j) acc[j] += w * yrow[j];
    }
    __shared__ float red[8][32][9];
    #pragma unroll
    for (int j = 0; j < 9; ++j) red[cseg][ocl][j] = acc[j];
    __syncthreads();
    for (int st = 4; st > 0; st >>= 1) {
        if (cseg < st) {
            #pragma unroll
            for (int j = 0; j < 9; ++j) red[cseg][ocl][j] += red[cseg + st][ocl][j];
        }
        __syncthreads();
    }
    if (cseg == 0) {
        float bias = gen_b[oc];
        #pragma unroll
        for (int j = 0; j < 9; ++j)
            dk[((size_t)b * TC + oc) * 9 + j] = red[0][ocl][j] + bias;
    }
}

// depthwise dynamic 3x3 -> channel-last padded bf16, pair-pipelined flush.
__global__ __launch_bounds__(1024) void dw_kernel(const float* __restrict__ x,
        const float* __restrict__ dk, __hip_bfloat16* __restrict__ outP) {
    int bid = blockIdx.x;
    int hs = bid & 7;
    int cc = (bid >> 3) & 7;
    int b  = bid >> 6;
    int t = threadIdx.x;
    int c  = t >> 5;
    int wq = t & 31;
    bool active = wq < 30;
    int w0 = wq * 4;
    int cg = cc * 32 + c;
    const float* xp = x + (size_t)(b * TC + cg) * THW;
    const float* dkp = dk + (size_t)(b * TC + cg) * 9;
    float k0[3], k1[3], k2[3];
    #pragma unroll
    for (int j = 0; j < 3; ++j) { k0[j] = dkp[j]; k1[j] = dkp[3 + j]; k2[j] = dkp[6 + j]; }

    __shared__ __align__(16) __hip_bfloat16 stage[2][2][32][124];

    int h0 = hs * 15;
    float A[6], B[6], C[6];
    auto loadrow = [&](int hh, float* V) {
        if (hh < 0 || hh >= TH) {
            #pragma unroll
            for (int j = 0; j < 6; ++j) V[j] = 0.f;
            return;
        }
        const float* row = xp + hh * TW;
        float4 v = *(const float4*)(row + w0);
        V[1] = v.x; V[2] = v.y; V[3] = v.z; V[4] = v.w;
        V[0] = (wq > 0)  ? row[w0 - 1] : 0.f;
        V[5] = (wq < 29) ? row[w0 + 4] : 0.f;
    };
    auto comp = [&](int r, int par, int sub) {
        if (!active) return;
        loadrow(h0 + r + 1, C);
        ushort4 pk;
        #pragma unroll
        for (int i = 0; i < 4; ++i) {
            float o = A[i] * k0[0] + A[i + 1] * k0[1] + A[i + 2] * k0[2]
                    + B[i] * k1[0] + B[i + 1] * k1[1] + B[i + 2] * k1[2]
                    + C[i] * k2[0] + C[i + 1] * k2[1] + C[i + 2] * k2[2];
            __hip_bfloat16 hb = __float2bfloat16(o);
            ushort u = *(ushort*)&hb;
            if (i == 0) pk.x = u; else if (i == 1) pk.y = u;
            else if (i == 2) pk.z = u; else pk.w = u;
        }
        *(ushort4*)&stage[par][sub][c][w0] = pk;
        #pragma unroll
        for (int j = 0; j < 6; ++j) { A[j] = B[j]; B[j] = C[j]; }
    };
    auto flushrow = [&](int r, int par, int sub, int tt) {
        int w = tt >> 2, part = tt & 3;
        ushort vals[8];
        #pragma unroll
        for (int j = 0; j < 8; ++j) vals[j] = *(const ushort*)&stage[par][sub][part * 8 + j][w];
        uint4 o;
        o.x = (uint)vals[0] | ((uint)vals[1] << 16);
        o.y = (uint)vals[2] | ((uint)vals[3] << 16);
        o.z = (uint)vals[4] | ((uint)vals[5] << 16);
        o.w = (uint)vals[6] | ((uint)vals[7] << 16);
        size_t pos = ((size_t)b * PH + (h0 + r + 1)) * PW + (w + 1);
        *(uint4*)((char*)outP + pos * 512 + cc * 64 + part * 16) = o;
    };

    if (active) { loadrow(h0 - 1, A); loadrow(h0, B); }
    comp(0, 0, 0); comp(1, 0, 1);
    __syncthreads();
    #pragma unroll 1
    for (int p = 1; p < 8; ++p) {
        int r0 = 2 * p;
        comp(r0, p & 1, 0);
        if (r0 + 1 < 15) comp(r0 + 1, p & 1, 1);
        if (t < 960) {
            int fr = t >= 480 ? 1 : 0;
            int tt = t - fr * 480;
            flushrow(2 * (p - 1) + fr, (p - 1) & 1, fr, tt);
        }
        __syncthreads();
    }
    if (t < 480) flushrow(14, 1, 0, t);
}

typedef const __attribute__((address_space(1))) char* gas_t;
typedef __attribute__((address_space(3))) char* las_t;
__device__ __forceinline__ void gload16(const char* g, char* l) {
    __builtin_amdgcn_global_load_lds((gas_t)g, (las_t)l, 16, 0, 0);
}

// Implicit GEMM (R6-proven, 146.5 us / MfmaUtil 41%): 128x128 tile, BK=64,
// 4 waves, global_load_lds w=16, pre-swizzled source + linear LDS + swizzled
// read, double-buffer, counted vmcnt(8), raw barriers, setprio, XCD swizzle.
__global__ __launch_bounds__(256, 2) void gemm_kernel(
        const __hip_bfloat16* __restrict__ outP,
        const __hip_bfloat16* __restrict__ Wp,
        const float* __restrict__ fuse_b,
        float* __restrict__ res) {
    __shared__ __align__(16) char lds[2][32768];
    const int t = threadIdx.x;
    const int lane = t & 63;
    const int wv = t >> 6;
    const int wo = wv >> 1;      // oc half
    const int wm = wv & 1;       // m half

    const int bid0 = blockIdx.x;
    const int logical = (bid0 & 7) * 225 + (bid0 >> 3);
    const int bn = logical & 1;      // oc tile (0..1)
    const int bm = logical >> 1;     // m tile (0..899)

    const char* gI = (const char*)outP;
    const char* gW = (const char*)Wp;

    const int rbp = (((lane & 7) ^ (lane >> 3)) << 4);
    int srcI[4], srcW[4];
    #pragma unroll
    for (int q = 0; q < 4; ++q) {
        int p = (q * 4 + wv) * 8 + (lane >> 3);
        int m = bm * 128 + p;
        int b = m / THW; int r = m - b * THW;
        int h = r / TW;  int w = r - h * TW;
        srcI[q] = (((b * PH + h) * PW + w) << 9) + rbp;
        srcW[q] = ((bn * 128 + p) << 9) + rbp;
    }
    const int segBase = wv * 1024;

    int aWb[4], aWs[4], aIb[4], aIs[4];
    #pragma unroll
    for (int i = 0; i < 4; ++i) {
        int rw = wo * 64 + i * 16 + (lane & 15);
        aWb[i] = rw * 128; aWs[i] = (rw & 7) << 4;
        int ri = wm * 64 + i * 16 + (lane & 15);
        aIb[i] = ri * 128; aIs[i] = (ri & 7) << 4;
    }
    const int klo = (lane >> 4) << 4;

    f32x4 acc[4][4];
    #pragma unroll
    for (int i = 0; i < 4; ++i) {
        #pragma unroll
        for (int j = 0; j < 4; ++j) {
            f32x4 z = {0.f, 0.f, 0.f, 0.f};
            acc[i][j] = z;
        }
    }

    auto step_offs = [&](int s, int& offI, int& offW) {
        int ij = s >> 2;
        int c0b = (s & 3) << 7;
        int di = ij / 3, dj = ij - (ij / 3) * 3;
        offI = ((di * PW + dj) << 9) + c0b;
        offW = (ij << 17) + c0b;
    };
    auto STAGE = [&](int buf, int s) {
        int offI, offW; step_offs(s, offI, offW);
        char* LI = &lds[buf][0];
        char* LW = &lds[buf][16384];
        #pragma unroll
        for (int q = 0; q < 4; ++q) {
            gload16(gI + srcI[q] + offI, LI + segBase + q * 4096);
            gload16(gW + srcW[q] + offW, LW + segBase + q * 4096);
        }
    };
    auto COMPUTE = [&](int buf) {
        const char* LI = &lds[buf][0];
        const char* LW = &lds[buf][16384];
        #pragma unroll
        for (int kk = 0; kk < 2; ++kk) {
            int ck = kk * 64 + klo;
            bf16x8 wf[4], iff[4];
            #pragma unroll
            for (int i = 0; i < 4; ++i)
                wf[i] = *(const bf16x8*)(LW + aWb[i] + (ck ^ aWs[i]));
            #pragma unroll
            for (int i = 0; i < 4; ++i)
                iff[i] = *(const bf16x8*)(LI + aIb[i] + (ck ^ aIs[i]));
            __builtin_amdgcn_s_setprio(1);
            #pragma unroll
            for (int o = 0; o < 4; ++o) {
                #pragma unroll
                for (int mi = 0; mi < 4; ++mi)
                    acc[o][mi] = __builtin_amdgcn_mfma_f32_16x16x32_bf16(
                        wf[o], iff[mi], acc[o][mi], 0, 0, 0);
            }
            __builtin_amdgcn_s_setprio(0);
        }
    };

    STAGE(0, 0);
    #pragma unroll 1
    for (int s = 0; s < 35; ++s) {
        int cur = s & 1;
        STAGE(cur ^ 1, s + 1);
        asm volatile("s_waitcnt vmcnt(8)" ::: "memory");
        __builtin_amdgcn_s_barrier();
        asm volatile("" ::: "memory");
        COMPUTE(cur);
        asm volatile("" ::: "memory");
        __builtin_amdgcn_s_barrier();
        asm volatile("" ::: "memory");
    }
    asm volatile("s_waitcnt vmcnt(0)" ::: "memory");
    __builtin_amdgcn_s_barrier();
    asm volatile("" ::: "memory");
    COMPUTE(1);

    int baseM[4];
    #pragma unroll
    for (int mt = 0; mt < 4; ++mt) {
        int m = bm * 128 + wm * 64 + mt * 16 + (lane & 15);
        int b = m / THW; int r = m - b * THW;
        baseM[mt] = b * (TOC * THW) + r;
    }
    const int ocb0 = bn * 128 + wo * 64 + ((lane >> 4) << 2);
    float bias[4][4];
    #pragma unroll
    for (int o = 0; o < 4; ++o) {
        #pragma unroll
        for (int g = 0; g < 4; ++g)
            bias[o][g] = fuse_b[ocb0 + o * 16 + g];
    }
    #pragma unroll
    for (int o = 0; o < 4; ++o) {
        #pragma unroll
        for (int mt = 0; mt < 4; ++mt) {
            #pragma unroll
            for (int g = 0; g < 4; ++g)
                res[baseM[mt] + (ocb0 + o * 16 + g) * THW] = acc[o][mt][g] + bias[o][g];
        }
    }
}

extern "C" void kernel_launch(void* const* d_in, const int* in_sizes, int n_in,
                              void* d_out, int out_size, void* d_ws, size_t ws_size,
                              hipStream_t stream) {
    const float* x      = (const float*)d_in[0];
    const float* y      = (const float*)d_in[1];
    const float* gen_w  = (const float*)d_in[2];
    const float* gen_b  = (const float*)d_in[3];
    const float* fuse_w = (const float*)d_in[4];
    const float* fuse_b = (const float*)d_in[5];
    float* out = (float*)d_out;
    char* ws = (char*)d_ws;

    __hip_bfloat16* outP = (__hip_bfloat16*)(ws);
    float* yp = (float*)(ws + YP_OFF);
    float* dk = (float*)(ws + DK_OFF);
    __hip_bfloat16* Wp = (__hip_bfloat16*)(ws + WP_OFF);

    pool_prep_kernel<<<7624, 128, 0, stream>>>(y, yp, fuse_w, Wp, (char*)outP);
    gen_kernel<<<64, 256, 0, stream>>>(yp, gen_w, gen_b, dk);
    dw_kernel<<<512, 1024, 0, stream>>>(x, dk, outP);
    gemm_kernel<<<1800, 256, 0, stream>>>(outP, Wp, fuse_b, out);
}

// Round 9
// 216.684 us; speedup vs baseline: 1.6133x; 1.0012x over previous
//
#include <hip/hip_runtime.h>
#include <hip/hip_bf16.h>
#include <stdint.h>

#define TB 8
#define TC 256
#define TH 120
#define TW 120
#define THW 14400
#define TOC 256
#define PH 122
#define PW 122

typedef short bf16x8 __attribute__((ext_vector_type(8)));
typedef float f32x4 __attribute__((ext_vector_type(4)));

// ---- workspace layout (bytes) ----
#define OUTP_BYTES ((size_t)TB * PH * PW * TC * 2)
#define YP_OFF     OUTP_BYTES
#define DK_OFF     (YP_OFF + (size_t)TB * TC * 9 * 4)
#define WP_OFF     (DK_OFF + (size_t)TB * TC * 9 * 4)

// Fat kernel: blocks 0..2047 = pool; 2048..3015 = halo zero; 3016..7623 = wprep.
__global__ __launch_bounds__(128) void pool_prep_kernel(
        const float* __restrict__ y, float* __restrict__ yp,
        const float* __restrict__ fuse_w, __hip_bfloat16* __restrict__ Wp,
        char* __restrict__ outP) {
    int blk = blockIdx.x;
    int t = threadIdx.x;
    __shared__ float red[128][3];
    if (blk < 2048) {
        // ---- pool: yp[b][c][ij] = mean of 40x40 block.
        // Coalesced: thread (rsub=t>>5, cq=t&31<30) reads float4 (k*4+rsub)*30+cq
        // -> 480B contiguous runs, 4 rows per instruction.  Row-band k/10 is
        // static (full unroll); column-band cq/10 resolved at reduce.
        int bc = blk;
        const float4* img = (const float4*)(y + (size_t)bc * THW);
        int cq = t & 31;
        int rsub = t >> 5;
        bool act = cq < 30;
        float a0 = 0.f, a1 = 0.f, a2 = 0.f;
        if (act) {
            #pragma unroll
            for (int k = 0; k < 30; ++k) {
                int row = k * 4 + rsub;
                float4 v = img[row * 30 + cq];
                float s = (v.x + v.y) + (v.z + v.w);
                if (k < 10) a0 += s; else if (k < 20) a1 += s; else a2 += s;
            }
        }
        red[t][0] = a0; red[t][1] = a1; red[t][2] = a2;
        __syncthreads();
        if (t < 9) {
            int bh = t / 3, bw = t - bh * 3;
            float a = 0.f;
            #pragma unroll
            for (int g = 0; g < 4; ++g)
                for (int q = 0; q < 10; ++q)
                    a += red[g * 32 + bw * 10 + q][bh];
            yp[bc * 9 + t] = a * (1.f / 1600.f);
        }
    } else if (blk < 3016) {
        // ---- halo zero: 123904 uint4 slots
        int i = (blk - 2048) * 128 + t;
        int pos_idx = i >> 5, part = i & 31;
        int b = pos_idx / 484; int k = pos_idx - b * 484;
        int h, w;
        if (k < 122)      { h = 0;   w = k; }
        else if (k < 244) { h = 121; w = k - 122; }
        else { int m = k - 244; h = 1 + (m >> 1); w = (m & 1) ? 121 : 0; }
        size_t pos = ((size_t)b * PH + h) * PW + w;
        uint4 z; z.x = 0u; z.y = 0u; z.z = 0u; z.w = 0u;
        *(uint4*)(outP + pos * 512 + part * 16) = z;
    } else {
        // ---- wprep: Wp[ij][oc][c] = bf16(fuse_w[oc][c][ij]), 589824 elems
        int i = (blk - 3016) * 128 + t;
        int ij = i >> 16;
        int oc = (i >> 8) & 255;
        int c  = i & 255;
        Wp[i] = __float2bfloat16(fuse_w[(oc * 256 + c) * 9 + ij]);
    }
}

// gen split: 64 blocks = (b, ocg of 32 oc); thread = (cseg 0..7, ocl 0..31)
__global__ __launch_bounds__(256) void gen_kernel(const float* __restrict__ yp,
        const float* __restrict__ gen_w, const float* __restrict__ gen_b,
        float* __restrict__ dk) {
    int blk = blockIdx.x;
    int b = blk >> 3, ocg = blk & 7;
    int t = threadIdx.x;
    int ocl = t & 31, cseg = t >> 5;
    int oc = ocg * 32 + ocl;
    __shared__ float yps[TC * 9];
    for (int i = t; i < TC * 9; i += 256) yps[i] = yp[b * TC * 9 + i];
    __syncthreads();
    float acc[9];
    #pragma unroll
    for (int j = 0; j < 9; ++j) acc[j] = 0.f;
    const float* wrow = gen_w + (size_t)oc * TC + cseg * 32;
    for (int c = 0; c < 32; ++c) {
        float w = wrow[c];
        const float* yrow = &yps[(cseg * 32 + c) * 9];
        #pragma unroll
        for (int j = 0; j < 9; ++j) acc[j] += w * yrow[j];
    }
    __shared__ float red[8][32][9];
    #pragma unroll
    for (int j = 0; j < 9; ++j) red[cseg][ocl][j] = acc[j];
    __syncthreads();
    for (int st = 4; st > 0; st >>= 1) {
        if (cseg < st) {
            #pragma unroll
            for (int j = 0; j < 9; ++j) red[cseg][ocl][j] += red[cseg + st][ocl][j];
        }
        __syncthreads();
    }
    if (cseg == 0) {
        float bias = gen_b[oc];
        #pragma unroll
        for (int j = 0; j < 9; ++j)
            dk[((size_t)b * TC + oc) * 9 + j] = red[0][ocl][j] + bias;
    }
}

// depthwise dynamic 3x3 -> channel-last padded bf16, pair-pipelined flush.
__global__ __launch_bounds__(1024) void dw_kernel(const float* __restrict__ x,
        const float* __restrict__ dk, __hip_bfloat16* __restrict__ outP) {
    int bid = blockIdx.x;
    int hs = bid & 7;
    int cc = (bid >> 3) & 7;
    int b  = bid >> 6;
    int t = threadIdx.x;
    int c  = t >> 5;
    int wq = t & 31;
    bool active = wq < 30;
    int w0 = wq * 4;
    int cg = cc * 32 + c;
    const float* xp = x + (size_t)(b * TC + cg) * THW;
    const float* dkp = dk + (size_t)(b * TC + cg) * 9;
    float k0[3], k1[3], k2[3];
    #pragma unroll
    for (int j = 0; j < 3; ++j) { k0[j] = dkp[j]; k1[j] = dkp[3 + j]; k2[j] = dkp[6 + j]; }

    __shared__ __align__(16) __hip_bfloat16 stage[2][2][32][124];

    int h0 = hs * 15;
    float A[6], B[6], C[6];
    auto loadrow = [&](int hh, float* V) {
        if (hh < 0 || hh >= TH) {
            #pragma unroll
            for (int j = 0; j < 6; ++j) V[j] = 0.f;
            return;
        }
        const float* row = xp + hh * TW;
        float4 v = *(const float4*)(row + w0);
        V[1] = v.x; V[2] = v.y; V[3] = v.z; V[4] = v.w;
        V[0] = (wq > 0)  ? row[w0 - 1] : 0.f;
        V[5] = (wq < 29) ? row[w0 + 4] : 0.f;
    };
    auto comp = [&](int r, int par, int sub) {
        if (!active) return;
        loadrow(h0 + r + 1, C);
        ushort4 pk;
        #pragma unroll
        for (int i = 0; i < 4; ++i) {
            float o = A[i] * k0[0] + A[i + 1] * k0[1] + A[i + 2] * k0[2]
                    + B[i] * k1[0] + B[i + 1] * k1[1] + B[i + 2] * k1[2]
                    + C[i] * k2[0] + C[i + 1] * k2[1] + C[i + 2] * k2[2];
            __hip_bfloat16 hb = __float2bfloat16(o);
            ushort u = *(ushort*)&hb;
            if (i == 0) pk.x = u; else if (i == 1) pk.y = u;
            else if (i == 2) pk.z = u; else pk.w = u;
        }
        *(ushort4*)&stage[par][sub][c][w0] = pk;
        #pragma unroll
        for (int j = 0; j < 6; ++j) { A[j] = B[j]; B[j] = C[j]; }
    };
    auto flushrow = [&](int r, int par, int sub, int tt) {
        int w = tt >> 2, part = tt & 3;
        ushort vals[8];
        #pragma unroll
        for (int j = 0; j < 8; ++j) vals[j] = *(const ushort*)&stage[par][sub][part * 8 + j][w];
        uint4 o;
        o.x = (uint)vals[0] | ((uint)vals[1] << 16);
        o.y = (uint)vals[2] | ((uint)vals[3] << 16);
        o.z = (uint)vals[4] | ((uint)vals[5] << 16);
        o.w = (uint)vals[6] | ((uint)vals[7] << 16);
        size_t pos = ((size_t)b * PH + (h0 + r + 1)) * PW + (w + 1);
        *(uint4*)((char*)outP + pos * 512 + cc * 64 + part * 16) = o;
    };

    if (active) { loadrow(h0 - 1, A); loadrow(h0, B); }
    comp(0, 0, 0); comp(1, 0, 1);
    __syncthreads();
    #pragma unroll 1
    for (int p = 1; p < 8; ++p) {
        int r0 = 2 * p;
        comp(r0, p & 1, 0);
        if (r0 + 1 < 15) comp(r0 + 1, p & 1, 1);
        if (t < 960) {
            int fr = t >= 480 ? 1 : 0;
            int tt = t - fr * 480;
            flushrow(2 * (p - 1) + fr, (p - 1) & 1, fr, tt);
        }
        __syncthreads();
    }
    if (t < 480) flushrow(14, 1, 0, t);
}

typedef const __attribute__((address_space(1))) char* gas_t;
typedef __attribute__((address_space(3))) char* las_t;
__device__ __forceinline__ void gload16(const char* g, char* l) {
    __builtin_amdgcn_global_load_lds((gas_t)g, (las_t)l, 16, 0, 0);
}

// Implicit GEMM (R6-proven, ~144 us / MfmaUtil 42%): 128x128 tile, BK=64,
// 4 waves, global_load_lds w=16, pre-swizzled source + linear LDS + swizzled
// read, double-buffer, counted vmcnt(8), raw barriers, setprio, XCD swizzle.
__global__ __launch_bounds__(256, 2) void gemm_kernel(
        const __hip_bfloat16* __restrict__ outP,
        const __hip_bfloat16* __restrict__ Wp,
        const float* __restrict__ fuse_b,
        float* __restrict__ res) {
    __shared__ __align__(16) char lds[2][32768];
    const int t = threadIdx.x;
    const int lane = t & 63;
    const int wv = t >> 6;
    const int wo = wv >> 1;      // oc half
    const int wm = wv & 1;       // m half

    const int bid0 = blockIdx.x;
    const int logical = (bid0 & 7) * 225 + (bid0 >> 3);
    const int bn = logical & 1;      // oc tile (0..1)
    const int bm = logical >> 1;     // m tile (0..899)

    const char* gI = (const char*)outP;
    const char* gW = (const char*)Wp;

    const int rbp = (((lane & 7) ^ (lane >> 3)) << 4);
    int srcI[4], srcW[4];
    #pragma unroll
    for (int q = 0; q < 4; ++q) {
        int p = (q * 4 + wv) * 8 + (lane >> 3);
        int m = bm * 128 + p;
        int b = m / THW; int r = m - b * THW;
        int h = r / TW;  int w = r - h * TW;
        srcI[q] = (((b * PH + h) * PW + w) << 9) + rbp;
        srcW[q] = ((bn * 128 + p) << 9) + rbp;
    }
    const int segBase = wv * 1024;

    int aWb[4], aWs[4], aIb[4], aIs[4];
    #pragma unroll
    for (int i = 0; i < 4; ++i) {
        int rw = wo * 64 + i * 16 + (lane & 15);
        aWb[i] = rw * 128; aWs[i] = (rw & 7) << 4;
        int ri = wm * 64 + i * 16 + (lane & 15);
        aIb[i] = ri * 128; aIs[i] = (ri & 7) << 4;
    }
    const int klo = (lane >> 4) << 4;

    f32x4 acc[4][4];
    #pragma unroll
    for (int i = 0; i < 4; ++i) {
        #pragma unroll
        for (int j = 0; j < 4; ++j) {
            f32x4 z = {0.f, 0.f, 0.f, 0.f};
            acc[i][j] = z;
        }
    }

    auto step_offs = [&](int s, int& offI, int& offW) {
        int ij = s >> 2;
        int c0b = (s & 3) << 7;
        int di = ij / 3, dj = ij - (ij / 3) * 3;
        offI = ((di * PW + dj) << 9) + c0b;
        offW = (ij << 17) + c0b;
    };
    auto STAGE = [&](int buf, int s) {
        int offI, offW; step_offs(s, offI, offW);
        char* LI = &lds[buf][0];
        char* LW = &lds[buf][16384];
        #pragma unroll
        for (int q = 0; q < 4; ++q) {
            gload16(gI + srcI[q] + offI, LI + segBase + q * 4096);
            gload16(gW + srcW[q] + offW, LW + segBase + q * 4096);
        }
    };
    auto COMPUTE = [&](int buf) {
        const char* LI = &lds[buf][0];
        const char* LW = &lds[buf][16384];
        #pragma unroll
        for (int kk = 0; kk < 2; ++kk) {
            int ck = kk * 64 + klo;
            bf16x8 wf[4], iff[4];
            #pragma unroll
            for (int i = 0; i < 4; ++i)
                wf[i] = *(const bf16x8*)(LW + aWb[i] + (ck ^ aWs[i]));
            #pragma unroll
            for (int i = 0; i < 4; ++i)
                iff[i] = *(const bf16x8*)(LI + aIb[i] + (ck ^ aIs[i]));
            __builtin_amdgcn_s_setprio(1);
            #pragma unroll
            for (int o = 0; o < 4; ++o) {
                #pragma unroll
                for (int mi = 0; mi < 4; ++mi)
                    acc[o][mi] = __builtin_amdgcn_mfma_f32_16x16x32_bf16(
                        wf[o], iff[mi], acc[o][mi], 0, 0, 0);
            }
            __builtin_amdgcn_s_setprio(0);
        }
    };

    STAGE(0, 0);
    #pragma unroll 1
    for (int s = 0; s < 35; ++s) {
        int cur = s & 1;
        STAGE(cur ^ 1, s + 1);
        asm volatile("s_waitcnt vmcnt(8)" ::: "memory");
        __builtin_amdgcn_s_barrier();
        asm volatile("" ::: "memory");
        COMPUTE(cur);
        asm volatile("" ::: "memory");
        __builtin_amdgcn_s_barrier();
        asm volatile("" ::: "memory");
    }
    asm volatile("s_waitcnt vmcnt(0)" ::: "memory");
    __builtin_amdgcn_s_barrier();
    asm volatile("" ::: "memory");
    COMPUTE(1);

    int baseM[4];
    #pragma unroll
    for (int mt = 0; mt < 4; ++mt) {
        int m = bm * 128 + wm * 64 + mt * 16 + (lane & 15);
        int b = m / THW; int r = m - b * THW;
        baseM[mt] = b * (TOC * THW) + r;
    }
    const int ocb0 = bn * 128 + wo * 64 + ((lane >> 4) << 2);
    float bias[4][4];
    #pragma unroll
    for (int o = 0; o < 4; ++o) {
        #pragma unroll
        for (int g = 0; g < 4; ++g)
            bias[o][g] = fuse_b[ocb0 + o * 16 + g];
    }
    #pragma unroll
    for (int o = 0; o < 4; ++o) {
        #pragma unroll
        for (int mt = 0; mt < 4; ++mt) {
            #pragma unroll
            for (int g = 0; g < 4; ++g)
                res[baseM[mt] + (ocb0 + o * 16 + g) * THW] = acc[o][mt][g] + bias[o][g];
        }
    }
}

extern "C" void kernel_launch(void* const* d_in, const int* in_sizes, int n_in,
                              void* d_out, int out_size, void* d_ws, size_t ws_size,
                              hipStream_t stream) {
    const float* x      = (const float*)d_in[0];
    const float* y      = (const float*)d_in[1];
    const float* gen_w  = (const float*)d_in[2];
    const float* gen_b  = (const float*)d_in[3];
    const float* fuse_w = (const float*)d_in[4];
    const float* fuse_b = (const float*)d_in[5];
    float* out = (float*)d_out;
    char* ws = (char*)d_ws;

    __hip_bfloat16* outP = (__hip_bfloat16*)(ws);
    float* yp = (float*)(ws + YP_OFF);
    float* dk = (float*)(ws + DK_OFF);
    __hip_bfloat16* Wp = (__hip_bfloat16*)(ws + WP_OFF);

    pool_prep_kernel<<<7624, 128, 0, stream>>>(y, yp, fuse_w, Wp, (char*)outP);
    gen_kernel<<<64, 256, 0, stream>>>(yp, gen_w, gen_b, dk);
    dw_kernel<<<512, 1024, 0, stream>>>(x, dk, outP);
    gemm_kernel<<<1800, 256, 0, stream>>>(outP, Wp, fuse_b, out);
}